// Round 3
// baseline (378.062 us; speedup 1.0000x reference)
//
#include <hip/hip_runtime.h>
#include <hip/hip_bf16.h>

// Causal sliding-window attention (window W incl. self), GQA 4:1, T=8192, D=128.
// Plan:
//   prep_k : key  fp32 [T][HK*128]  -> bf16 Kb [HK][T][128]   (de-interleave + cvt)
//   prep_v : value fp32 [T][HK*128] -> bf16 Vt [HK][128][T]   (LDS-tiled transpose)
//   attn_main: flash attention, swapped-operand MFMA:
//     S^T = mfma(K, Q^T)  -> lane holds 4 kv scores for ONE q row (q = lane&15)
//     O^T = mfma(V^T, P^T)-> P^T via per-wave LDS round trip (C-layout -> B-layout)
//   Softmax runs in exp2 domain: sv = s * SCALE*log2(e); p = exp2(sv - m2);
//   lse = ln2 * (m2 + log2(lsum)).  No __syncthreads in the main loop.

#define T_SEQ 8192
#define H_Q   16
#define HK_KV 4
#define D_HD  128
#define W_WIN 512
#define SCL2E 0.12753785397738803f   // 128^-0.5 * log2(e)
#define LN2   0.6931471805599453f

typedef __bf16 bf16_t;
typedef bf16_t bf16x8 __attribute__((ext_vector_type(8)));
typedef float  f32x4  __attribute__((ext_vector_type(4)));

union U4 { uint2 u; bf16_t b[4]; };

__device__ inline bf16x8 to_bf8(float4 a, float4 b) {
    bf16x8 r;
    r[0] = (bf16_t)a.x; r[1] = (bf16_t)a.y; r[2] = (bf16_t)a.z; r[3] = (bf16_t)a.w;
    r[4] = (bf16_t)b.x; r[5] = (bf16_t)b.y; r[6] = (bf16_t)b.z; r[7] = (bf16_t)b.w;
    return r;
}

// ---------- prepass: K convert ----------
__global__ __launch_bounds__(256) void prep_k(const float* __restrict__ key,
                                              bf16_t* __restrict__ Kb) {
    int e = (blockIdx.x * 256 + threadIdx.x) * 4;   // flat fp32 index, 4 per thread
    int t  = e >> 9;          // /512
    int c  = e & 511;
    int hk = c >> 7;
    int d  = c & 127;
    float4 v = *(const float4*)(key + e);
    U4 p;
    p.b[0] = (bf16_t)v.x; p.b[1] = (bf16_t)v.y; p.b[2] = (bf16_t)v.z; p.b[3] = (bf16_t)v.w;
    *(uint2*)(void*)(Kb + ((size_t)hk * T_SEQ + t) * 128 + d) = p.u;
}

// ---------- prepass: V transpose ----------
__global__ __launch_bounds__(256) void prep_v(const float* __restrict__ val,
                                              bf16_t* __restrict__ Vt) {
    __shared__ ushort tile[64][68];   // [t][d], padded stride 136B
    int b   = blockIdx.x;
    int hk  = b >> 8;                 // 256 blocks per hk
    int rem = b & 255;
    int t0  = (rem & 127) << 6;
    int d0  = (rem >> 7) << 6;
    int tid = threadIdx.x;

    int i  = tid >> 2;                // 0..63 source row (t)
    int j0 = (tid & 3) << 4;          // 0,16,32,48 (d)
    const float* src = val + (size_t)(t0 + i) * 512 + hk * 128 + d0 + j0;
#pragma unroll
    for (int k = 0; k < 4; ++k) {
        float4 v = *(const float4*)(src + 4 * k);
        U4 p;
        p.b[0] = (bf16_t)v.x; p.b[1] = (bf16_t)v.y; p.b[2] = (bf16_t)v.z; p.b[3] = (bf16_t)v.w;
        *(uint2*)(void*)&tile[i][j0 + 4 * k] = p.u;
    }
    __syncthreads();
    int dd = tid >> 2;                // 0..63 dest row (d)
    int tq = (tid & 3) << 4;          // t chunk
    bf16_t* dst = Vt + ((size_t)hk * 128 + d0 + dd) * T_SEQ + t0 + tq;
#pragma unroll
    for (int k = 0; k < 4; ++k) {
        ushort4 u;
        u.x = tile[tq + 4 * k + 0][dd];
        u.y = tile[tq + 4 * k + 1][dd];
        u.z = tile[tq + 4 * k + 2][dd];
        u.w = tile[tq + 4 * k + 3][dd];
        *(ushort4*)(void*)(dst + 4 * k) = u;
    }
}

// ---------- main attention ----------
__global__ __launch_bounds__(256) void attn_main(const float* __restrict__ qg,
                                                 const bf16_t* __restrict__ Kb,
                                                 const bf16_t* __restrict__ Vt,
                                                 float* __restrict__ out) {
    // per-wave P buffer: [16 q][40 bf16] (32 data + 8 pad; 80B rows, 16B-aligned)
    __shared__ ushort Plds[4][16][40] __attribute__((aligned(16)));

    const int gx = blockIdx.x;
    const int h  = gx & 15;
    const int hk = h >> 2;
    const int qb = gx >> 4;
    const int tid  = threadIdx.x;
    const int wv   = tid >> 6;
    const int lane = tid & 63;
    const int lq   = lane & 15;      // q row within wave / A-frag row / B-frag col
    const int g    = lane >> 4;      // k-group
    const int q0w  = qb * 64 + wv * 16;
    const int qa   = q0w + lq;       // absolute query row for this lane

    // Q B-frags: lane holds Q[qa][kc*32 + 8g + j], j=0..7
    bf16x8 qf[4];
    const float* qp = qg + (size_t)qa * 2048 + h * 128 + 8 * g;
#pragma unroll
    for (int kc = 0; kc < 4; ++kc) {
        float4 a = *(const float4*)(qp + kc * 32);
        float4 b = *(const float4*)(qp + kc * 32 + 4);
        qf[kc] = to_bf8(a, b);
    }

    f32x4 acc[8];
#pragma unroll
    for (int i = 0; i < 8; ++i) acc[i] = (f32x4){0.f, 0.f, 0.f, 0.f};
    float mrun = -1e4f;   // finite floor (log2 domain): masked scores exp2 -> 0, never NaN
    float lsum = 0.f;

    const bf16_t* kb_ = Kb + (size_t)hk * T_SEQ * 128;
    const bf16_t* vb_ = Vt + (size_t)hk * 128 * T_SEQ;

    int lo  = q0w - (W_WIN - 1);
    int kt0 = lo > 0 ? (lo >> 5) : 0;
    int kt1 = (q0w + 15) >> 5;

    for (int kt = kt0; kt <= kt1; ++kt) {
        const int kbs = kt << 5;

        // ---- QK^T (swapped): S^T = K * Q^T, two 16-row k-tiles ----
        f32x4 s0 = {0.f, 0.f, 0.f, 0.f}, s1 = {0.f, 0.f, 0.f, 0.f};
        const bf16_t* kp = kb_ + (size_t)(kbs + lq) * 128 + 8 * g;
#pragma unroll
        for (int kc = 0; kc < 4; ++kc) {
            bf16x8 k0 = *(const bf16x8*)(kp + kc * 32);
            bf16x8 k1 = *(const bf16x8*)(kp + 16 * 128 + kc * 32);
            s0 = __builtin_amdgcn_mfma_f32_16x16x32_bf16(k0, qf[kc], s0, 0, 0, 0);
            s1 = __builtin_amdgcn_mfma_f32_16x16x32_bf16(k1, qf[kc], s1, 0, 0, 0);
        }

        // ---- scale into log2 domain + window mask (kv = kbs + {0,16} + 4g + r) ----
        float sv[8];
#pragma unroll
        for (int r = 0; r < 4; ++r) {
            int kv0 = kbs + 4 * g + r;
            int kv1 = kv0 + 16;
            sv[r]     = (kv0 >= qa - (W_WIN - 1) && kv0 <= qa) ? s0[r] * SCL2E : -1e30f;
            sv[4 + r] = (kv1 >= qa - (W_WIN - 1) && kv1 <= qa) ? s1[r] * SCL2E : -1e30f;
        }

        // ---- online softmax (rows are lane-local: reduce over 4 lanes xor 16,32) ----
        float tmax = sv[0];
#pragma unroll
        for (int i = 1; i < 8; ++i) tmax = fmaxf(tmax, sv[i]);
        tmax = fmaxf(tmax, __shfl_xor(tmax, 16));
        tmax = fmaxf(tmax, __shfl_xor(tmax, 32));

        if (!__all(tmax <= mrun + 11.54f)) {  // T13 defer-max (8 nats = 11.54 bits)
            float mnew  = fmaxf(mrun, tmax);
            float alpha = exp2f(mrun - mnew);
            lsum *= alpha;
#pragma unroll
            for (int i = 0; i < 8; ++i) acc[i] *= alpha;
            mrun = mnew;
        }

        float p[8];
        float psum = 0.f;
#pragma unroll
        for (int i = 0; i < 8; ++i) { p[i] = exp2f(sv[i] - mrun); psum += p[i]; }
        psum += __shfl_xor(psum, 16);
        psum += __shfl_xor(psum, 32);
        lsum += psum;

        // ---- P round trip: C-layout write (4 consecutive kv per lane) ----
        U4 w0, w1;
        w0.b[0] = (bf16_t)p[0]; w0.b[1] = (bf16_t)p[1]; w0.b[2] = (bf16_t)p[2]; w0.b[3] = (bf16_t)p[3];
        w1.b[0] = (bf16_t)p[4]; w1.b[1] = (bf16_t)p[5]; w1.b[2] = (bf16_t)p[6]; w1.b[3] = (bf16_t)p[7];
        *(uint2*)(void*)&Plds[wv][lq][4 * g]      = w0.u;
        *(uint2*)(void*)&Plds[wv][lq][16 + 4 * g] = w1.u;
        asm volatile("s_waitcnt lgkmcnt(0)" ::: "memory");  // same-wave cross-lane visibility
        bf16x8 pb = *(const bf16x8*)(void*)&Plds[wv][lq][8 * g];  // B-frag: P[q][8g..8g+7]

        // ---- PV: O^T += V^T * P^T ----
        const bf16_t* vp = vb_ + (size_t)lq * T_SEQ + kbs + 8 * g;
#pragma unroll
        for (int dt = 0; dt < 8; ++dt) {
            bf16x8 vf = *(const bf16x8*)(vp + (size_t)dt * 16 * T_SEQ);
            acc[dt] = __builtin_amdgcn_mfma_f32_16x16x32_bf16(vf, pb, acc[dt], 0, 0, 0);
        }
    }

    // ---- epilogue: O^T C-layout: d = dt*16 + 4g + r, q = lq ----
    float inv = 1.0f / lsum;
#pragma unroll
    for (int dt = 0; dt < 8; ++dt) {
        float4 o;
        o.x = acc[dt][0] * inv; o.y = acc[dt][1] * inv;
        o.z = acc[dt][2] * inv; o.w = acc[dt][3] * inv;
        *(float4*)(out + (size_t)qa * 2048 + h * 128 + dt * 16 + 4 * g) = o;
    }
    if (lane < 16) {
        out[(size_t)T_SEQ * 2048 + (size_t)h * T_SEQ + qa] =
            LN2 * (mrun + log2f(lsum));
    }
}

extern "C" void kernel_launch(void* const* d_in, const int* in_sizes, int n_in,
                              void* d_out, int out_size, void* d_ws, size_t ws_size,
                              hipStream_t stream) {
    const float* q = (const float*)d_in[0];
    const float* k = (const float*)d_in[1];
    const float* v = (const float*)d_in[2];
    float* out = (float*)d_out;

    bf16_t* Kb = (bf16_t*)d_ws;                          // [HK][T][128] bf16
    bf16_t* Vt = Kb + (size_t)HK_KV * T_SEQ * D_HD;      // [HK][128][T] bf16

    prep_k<<<(T_SEQ * HK_KV * D_HD) / (256 * 4), 256, 0, stream>>>(k, Kb);
    prep_v<<<HK_KV * (T_SEQ / 64) * (D_HD / 64), 256, 0, stream>>>(v, Vt);
    attn_main<<<(T_SEQ / 64) * H_Q, 256, 0, stream>>>(q, Kb, Vt, out);
}

// Round 5
// 222.875 us; speedup vs baseline: 1.6963x; 1.6963x over previous
//
#include <hip/hip_runtime.h>
#include <hip/hip_bf16.h>

// Causal sliding-window attention (window W incl. self), GQA 4:1, T=8192, D=128.
//   prep_k : key  fp32 [T][HK*128]  -> bf16 Kb [HK][T][128]
//   prep_v : value fp32 [T][HK*128] -> bf16 Vt [HK][128][T]   (LDS-tiled transpose)
//   attn_main: flash attention, block-cooperative LDS-staged KV (double-buffered,
//   global_load_lds w16, XOR-swizzled via pre-swizzled global source), swapped-
//   operand MFMA (S^T = K*Q^T, O^T = V^T*P^T), softmax in exp2 domain.

#define T_SEQ 8192
#define H_Q   16
#define HK_KV 4
#define D_HD  128
#define W_WIN 512
#define SCL2E 0.12753785397738803f   // 128^-0.5 * log2(e)
#define LN2   0.6931471805599453f

typedef __bf16 bf16_t;
typedef bf16_t bf16x8 __attribute__((ext_vector_type(8)));
typedef float  f32x4  __attribute__((ext_vector_type(4)));
typedef ushort us8    __attribute__((ext_vector_type(8)));

union U4 { uint2 u; bf16_t b[4]; };

__device__ inline bf16x8 to_bf8(float4 a, float4 b) {
    bf16x8 r;
    r[0] = (bf16_t)a.x; r[1] = (bf16_t)a.y; r[2] = (bf16_t)a.z; r[3] = (bf16_t)a.w;
    r[4] = (bf16_t)b.x; r[5] = (bf16_t)b.y; r[6] = (bf16_t)b.z; r[7] = (bf16_t)b.w;
    return r;
}

__device__ __forceinline__ void gld16(const void* g, void* l) {
    __builtin_amdgcn_global_load_lds(
        (const __attribute__((address_space(1))) void*)g,
        (__attribute__((address_space(3))) void*)l, 16, 0, 0);
}

// ---------- prepass: K convert ----------
__global__ __launch_bounds__(256) void prep_k(const float* __restrict__ key,
                                              bf16_t* __restrict__ Kb) {
    int e = (blockIdx.x * 256 + threadIdx.x) * 4;
    int t  = e >> 9;
    int c  = e & 511;
    int hk = c >> 7;
    int d  = c & 127;
    float4 v = *(const float4*)(key + e);
    U4 p;
    p.b[0] = (bf16_t)v.x; p.b[1] = (bf16_t)v.y; p.b[2] = (bf16_t)v.z; p.b[3] = (bf16_t)v.w;
    *(uint2*)(void*)(Kb + ((size_t)hk * T_SEQ + t) * 128 + d) = p.u;
}

// ---------- prepass: V transpose ----------
__global__ __launch_bounds__(256) void prep_v(const float* __restrict__ val,
                                              bf16_t* __restrict__ Vt) {
    __shared__ ushort tile[64][68];   // [t][d], padded stride 136B
    int b   = blockIdx.x;
    int hk  = b >> 8;
    int rem = b & 255;
    int t0  = (rem & 127) << 6;
    int d0  = (rem >> 7) << 6;
    int tid = threadIdx.x;

    int i  = tid >> 2;                // 0..63 source row (t)
    int j0 = (tid & 3) << 4;          // d chunk
    const float* src = val + (size_t)(t0 + i) * 512 + hk * 128 + d0 + j0;
#pragma unroll
    for (int k = 0; k < 4; ++k) {
        float4 v = *(const float4*)(src + 4 * k);
        U4 p;
        p.b[0] = (bf16_t)v.x; p.b[1] = (bf16_t)v.y; p.b[2] = (bf16_t)v.z; p.b[3] = (bf16_t)v.w;
        *(uint2*)(void*)&tile[i][j0 + 4 * k] = p.u;
    }
    __syncthreads();
    // phase 2: 16B stores, 8 lanes cover one d-row (128B contiguous per row)
    int dd8 = tid >> 3;               // 0..31
    int tq  = (tid & 7) << 3;         // 0..56
#pragma unroll
    for (int half = 0; half < 2; ++half) {
        int dd = half * 32 + dd8;
        us8 u;
#pragma unroll
        for (int j = 0; j < 8; ++j) u[j] = tile[tq + j][dd];
        bf16_t* dst = Vt + ((size_t)hk * 128 + d0 + dd) * T_SEQ + t0 + tq;
        *(us8*)(void*)dst = u;
    }
}

// ---------- main attention ----------
__global__ __launch_bounds__(256) void attn_main(const float* __restrict__ qg,
                                                 const bf16_t* __restrict__ Kb,
                                                 const bf16_t* __restrict__ Vt,
                                                 float* __restrict__ out) {
    // staged KV (double-buffered): K tile [32][128], V^T tile [128][32], both 8KB
    __shared__ ushort Kls[2][4096] __attribute__((aligned(16)));
    __shared__ ushort Vls[2][4096] __attribute__((aligned(16)));
    __shared__ ushort Plds[4][16][40] __attribute__((aligned(16)));

    // bijective XCD swizzle: XCD x -> heads {2x,2x+1} (one hk = 4MB KV = L2 size),
    // contiguous qb per head so co-resident blocks share the KV window in L2.
    const int bid = blockIdx.x;
    const int w   = (bid & 7) * 256 + (bid >> 3);   // 2048 = 8 XCD * 256
    const int h   = w >> 7;
    const int qb  = w & 127;
    const int hk  = h >> 2;
    const int tid  = threadIdx.x;
    const int wv   = tid >> 6;
    const int lane = tid & 63;
    const int lq   = lane & 15;
    const int g    = lane >> 4;
    const int q0b  = qb * 64;
    const int q0w  = q0b + wv * 16;
    const int qa   = q0w + lq;

    // Q B-frags: lane holds Q[qa][kc*32 + 8g + j]
    bf16x8 qf[4];
    const float* qp = qg + (size_t)qa * 2048 + h * 128 + 8 * g;
#pragma unroll
    for (int kc = 0; kc < 4; ++kc) {
        float4 a = *(const float4*)(qp + kc * 32);
        float4 b = *(const float4*)(qp + kc * 32 + 4);
        qf[kc] = to_bf8(a, b);
    }

    f32x4 acc[8];
#pragma unroll
    for (int i = 0; i < 8; ++i) acc[i] = (f32x4){0.f, 0.f, 0.f, 0.f};
    float mrun = -1e4f;
    float lsum = 0.f;

    const bf16_t* kb_ = Kb + (size_t)hk * T_SEQ * 128;
    const bf16_t* vb_ = Vt + (size_t)hk * 128 * T_SEQ;

    const int lob  = q0b - (W_WIN - 1);
    const int ktb0 = lob > 0 ? (lob >> 5) : 0;
    const int ktb1 = (q0b + 63) >> 5;
    const int wlow = q0w - (W_WIN - 1);   // wave's lowest valid kv

    // stage one 32-row KV tile into buffer bf (4 x gld16 per thread).
    // source global address pre-swizzled (XOR involution), LDS dest linear,
    // reads apply the same XOR (rule #21: both-sides-or-neither).
    //   K: [32 row][16 chunk16B]  chunk-slot c holds global chunk c ^ (row&7)
    //   V: [128 row][4 chunk16B]  chunk-slot c holds global chunk c ^ ((row>>1)&3)
    auto stage = [&](int bf, int kbs) {
#pragma unroll
        for (int is = 0; is < 2; ++is) {
            int slot = is * 256 + tid;
            int krow = slot >> 4;
            int kch  = (slot & 15) ^ (krow & 7);
            gld16(kb_ + (size_t)(kbs + krow) * 128 + kch * 8,
                  (char*)&Kls[bf][0] + slot * 16);
        }
#pragma unroll
        for (int is = 0; is < 2; ++is) {
            int slot = is * 256 + tid;
            int vrow = slot >> 2;
            int vch  = (slot & 3) ^ ((vrow >> 1) & 3);
            gld16(vb_ + (size_t)vrow * T_SEQ + kbs + vch * 8,
                  (char*)&Vls[bf][0] + slot * 16);
        }
    };

    int buf = 0;
    stage(0, ktb0 << 5);
    asm volatile("s_waitcnt vmcnt(0)" ::: "memory");
    __syncthreads();

    for (int kt = ktb0; kt <= ktb1; ++kt) {
        const int kbs = kt << 5;
        if (kt < ktb1) stage(buf ^ 1, (kt + 1) << 5);

        // wave-uniform activity test: tile overlaps [q0w-511, q0w+15]
        if (kbs + 31 >= wlow && kbs <= q0w + 15) {
            // ---- QK^T from swizzled K LDS tile ----
            f32x4 s0 = {0.f, 0.f, 0.f, 0.f}, s1 = {0.f, 0.f, 0.f, 0.f};
            const char* kb0  = (const char*)&Kls[buf][0] + lq * 256;
            const int   kxor = (lq & 7) << 4;
#pragma unroll
            for (int kc = 0; kc < 4; ++kc) {
                int cb = kc * 64 + g * 16;
                bf16x8 k0 = *(const bf16x8*)(kb0 + (cb ^ kxor));
                bf16x8 k1 = *(const bf16x8*)(kb0 + 4096 + (cb ^ kxor));
                s0 = __builtin_amdgcn_mfma_f32_16x16x32_bf16(k0, qf[kc], s0, 0, 0, 0);
                s1 = __builtin_amdgcn_mfma_f32_16x16x32_bf16(k1, qf[kc], s1, 0, 0, 0);
            }

            // ---- scale into log2 domain + window mask ----
            float sv[8];
#pragma unroll
            for (int r = 0; r < 4; ++r) {
                int kv0 = kbs + 4 * g + r;
                int kv1 = kv0 + 16;
                sv[r]     = (kv0 >= qa - (W_WIN - 1) && kv0 <= qa) ? s0[r] * SCL2E : -1e30f;
                sv[4 + r] = (kv1 >= qa - (W_WIN - 1) && kv1 <= qa) ? s1[r] * SCL2E : -1e30f;
            }

            // ---- online softmax (row = lane-local; reduce over xor 16,32) ----
            float tmax = sv[0];
#pragma unroll
            for (int i = 1; i < 8; ++i) tmax = fmaxf(tmax, sv[i]);
            tmax = fmaxf(tmax, __shfl_xor(tmax, 16));
            tmax = fmaxf(tmax, __shfl_xor(tmax, 32));

            if (!__all(tmax <= mrun + 11.54f)) {   // defer-max (8 nats)
                float mnew  = fmaxf(mrun, tmax);
                float alpha = exp2f(mrun - mnew);
                lsum *= alpha;
#pragma unroll
                for (int i = 0; i < 8; ++i) acc[i] *= alpha;
                mrun = mnew;
            }

            float p[8];
            float psum = 0.f;
#pragma unroll
            for (int i = 0; i < 8; ++i) { p[i] = exp2f(sv[i] - mrun); psum += p[i]; }
            psum += __shfl_xor(psum, 16);
            psum += __shfl_xor(psum, 32);
            lsum += psum;

            // ---- P round trip (per-wave LDS, same-wave only) ----
            U4 w0, w1;
            w0.b[0] = (bf16_t)p[0]; w0.b[1] = (bf16_t)p[1]; w0.b[2] = (bf16_t)p[2]; w0.b[3] = (bf16_t)p[3];
            w1.b[0] = (bf16_t)p[4]; w1.b[1] = (bf16_t)p[5]; w1.b[2] = (bf16_t)p[6]; w1.b[3] = (bf16_t)p[7];
            *(uint2*)(void*)&Plds[wv][lq][4 * g]      = w0.u;
            *(uint2*)(void*)&Plds[wv][lq][16 + 4 * g] = w1.u;
            asm volatile("s_waitcnt lgkmcnt(0)" ::: "memory");
            bf16x8 pb = *(const bf16x8*)(void*)&Plds[wv][lq][8 * g];

            // ---- PV from swizzled V^T LDS tile ----
            const char* vb0 = (const char*)&Vls[buf][0] + lq * 64
                            + ((g ^ ((lq >> 1) & 3)) << 4);
#pragma unroll
            for (int dt = 0; dt < 8; ++dt) {
                bf16x8 vf = *(const bf16x8*)(vb0 + dt * 1024);
                acc[dt] = __builtin_amdgcn_mfma_f32_16x16x32_bf16(vf, pb, acc[dt], 0, 0, 0);
            }
        }

        asm volatile("s_waitcnt vmcnt(0)" ::: "memory");
        __syncthreads();
        buf ^= 1;
    }

    // ---- epilogue ----
    float inv = 1.0f / lsum;
#pragma unroll
    for (int dt = 0; dt < 8; ++dt) {
        float4 o;
        o.x = acc[dt][0] * inv; o.y = acc[dt][1] * inv;
        o.z = acc[dt][2] * inv; o.w = acc[dt][3] * inv;
        *(float4*)(out + (size_t)qa * 2048 + h * 128 + dt * 16 + 4 * g) = o;
    }
    if (lane < 16) {
        out[(size_t)T_SEQ * 2048 + (size_t)h * T_SEQ + qa] =
            LN2 * (mrun + log2f(lsum));
    }
}

extern "C" void kernel_launch(void* const* d_in, const int* in_sizes, int n_in,
                              void* d_out, int out_size, void* d_ws, size_t ws_size,
                              hipStream_t stream) {
    const float* q = (const float*)d_in[0];
    const float* k = (const float*)d_in[1];
    const float* v = (const float*)d_in[2];
    float* out = (float*)d_out;

    bf16_t* Kb = (bf16_t*)d_ws;
    bf16_t* Vt = Kb + (size_t)HK_KV * T_SEQ * D_HD;

    prep_k<<<(T_SEQ * HK_KV * D_HD) / (256 * 4), 256, 0, stream>>>(k, Kb);
    prep_v<<<HK_KV * (T_SEQ / 64) * (D_HD / 64), 256, 0, stream>>>(v, Vt);
    attn_main<<<(T_SEQ / 64) * H_Q, 256, 0, stream>>>(q, Kb, Vt, out);
}

// Round 6
// 209.916 us; speedup vs baseline: 1.8010x; 1.0617x over previous
//
#include <hip/hip_runtime.h>
#include <hip/hip_bf16.h>

// Causal sliding-window attention (window W incl. self), GQA 4:1, T=8192, D=128.
//   prep_kv: key->bf16 Kb [HK][T][128]; value->bf16 Vt [HK][128][T] (transposed)
//   attn_main: flash attention, block-coop LDS-staged KV (double-buffered,
//   global_load_lds w16, XOR-swizzle via pre-swizzled source), swapped-operand
//   MFMA (S^T = K*Q^T, O^T = V^T*P^T), exp2-domain softmax, interior fast path,
//   all hot-loop addresses precomputed (saddr-form staging, 0 VALU/tile addr).

#define T_SEQ 8192
#define H_Q   16
#define HK_KV 4
#define D_HD  128
#define W_WIN 512
#define SCL2E 0.12753785397738803f   // 128^-0.5 * log2(e)
#define LN2   0.6931471805599453f

typedef __bf16 bf16_t;
typedef bf16_t bf16x8 __attribute__((ext_vector_type(8)));
typedef float  f32x4  __attribute__((ext_vector_type(4)));
typedef ushort us8    __attribute__((ext_vector_type(8)));

union U4 { uint2 u; bf16_t b[4]; };

__device__ inline bf16x8 to_bf8(float4 a, float4 b) {
    bf16x8 r;
    r[0] = (bf16_t)a.x; r[1] = (bf16_t)a.y; r[2] = (bf16_t)a.z; r[3] = (bf16_t)a.w;
    r[4] = (bf16_t)b.x; r[5] = (bf16_t)b.y; r[6] = (bf16_t)b.z; r[7] = (bf16_t)b.w;
    return r;
}

__device__ __forceinline__ void gld16(const void* g, void* l) {
    __builtin_amdgcn_global_load_lds(
        (const __attribute__((address_space(1))) void*)g,
        (__attribute__((address_space(3))) void*)l, 16, 0, 0);
}

// ---------- merged prepass ----------
__global__ __launch_bounds__(256) void prep_kv(const float* __restrict__ key,
                                               const float* __restrict__ val,
                                               bf16_t* __restrict__ Kb,
                                               bf16_t* __restrict__ Vt) {
    __shared__ ushort tile[64][68];   // used by the V branch only
    const int tid = threadIdx.x;
    if (blockIdx.x < 4096) {
        int e = ((int)blockIdx.x * 256 + tid) * 4;
        int t  = e >> 9;
        int c  = e & 511;
        int hk = c >> 7;
        int d  = c & 127;
        float4 v = *(const float4*)(key + e);
        U4 p;
        p.b[0] = (bf16_t)v.x; p.b[1] = (bf16_t)v.y; p.b[2] = (bf16_t)v.z; p.b[3] = (bf16_t)v.w;
        *(uint2*)(void*)(Kb + ((size_t)hk * T_SEQ + t) * 128 + d) = p.u;
        return;
    }
    int b   = blockIdx.x - 4096;
    int hk  = b >> 8;
    int rem = b & 255;
    int t0  = (rem & 127) << 6;
    int d0  = (rem >> 7) << 6;

    int i  = tid >> 2;                // source row (t)
    int j0 = (tid & 3) << 4;          // d chunk
    const float* src = val + (size_t)(t0 + i) * 512 + hk * 128 + d0 + j0;
#pragma unroll
    for (int k = 0; k < 4; ++k) {
        float4 v = *(const float4*)(src + 4 * k);
        U4 p;
        p.b[0] = (bf16_t)v.x; p.b[1] = (bf16_t)v.y; p.b[2] = (bf16_t)v.z; p.b[3] = (bf16_t)v.w;
        *(uint2*)(void*)&tile[i][j0 + 4 * k] = p.u;
    }
    __syncthreads();
    int dd8 = tid >> 3;
    int tq  = (tid & 7) << 3;
#pragma unroll
    for (int half = 0; half < 2; ++half) {
        int dd = half * 32 + dd8;
        us8 u;
#pragma unroll
        for (int j = 0; j < 8; ++j) u[j] = tile[tq + j][dd];
        bf16_t* dst = Vt + ((size_t)hk * 128 + d0 + dd) * T_SEQ + t0 + tq;
        *(us8*)(void*)dst = u;
    }
}

// ---------- main attention ----------
__global__ __launch_bounds__(256) void attn_main(const float* __restrict__ qg,
                                                 const bf16_t* __restrict__ Kb,
                                                 const bf16_t* __restrict__ Vt,
                                                 float* __restrict__ out) {
    __shared__ ushort Kls[2][4096] __attribute__((aligned(16)));  // [32 r][16 ch] swz
    __shared__ ushort Vls[2][4096] __attribute__((aligned(16)));  // [128 r][4 ch] swz
    __shared__ ushort Plds[4][16][40] __attribute__((aligned(16)));

    // bijective XCD swizzle: XCD x -> heads {2x,2x+1}; contiguous qb within head
    const int bid = blockIdx.x;
    const int w   = (bid & 7) * 256 + (bid >> 3);
    const int h   = w >> 7;
    const int qb  = w & 127;
    const int hk  = h >> 2;
    const int tid  = threadIdx.x;
    const int wv   = tid >> 6;
    const int lane = tid & 63;
    const int lq   = lane & 15;
    const int g    = lane >> 4;
    const int q0b  = qb * 64;
    const int q0w  = q0b + wv * 16;
    const int qa   = q0w + lq;

    // Q B-frags
    bf16x8 qf[4];
    const float* qp = qg + (size_t)qa * 2048 + h * 128 + 8 * g;
#pragma unroll
    for (int kc = 0; kc < 4; ++kc) {
        float4 a = *(const float4*)(qp + kc * 32);
        float4 b = *(const float4*)(qp + kc * 32 + 4);
        qf[kc] = to_bf8(a, b);
    }

    f32x4 acc[8];
#pragma unroll
    for (int i = 0; i < 8; ++i) acc[i] = (f32x4){0.f, 0.f, 0.f, 0.f};
    float mrun = -1e4f;
    float lsum = 0.f;

    const bf16_t* kb_ = Kb + (size_t)hk * T_SEQ * 128;
    const bf16_t* vb_ = Vt + (size_t)hk * 128 * T_SEQ;

    const int lob  = q0b - (W_WIN - 1);
    const int ktb0 = lob > 0 ? (lob >> 5) : 0;
    const int ktb1 = (q0b + 63) >> 5;
    const int wlow = q0w - (W_WIN - 1);
    const int bq   = 4 * g - qa + 511;   // mask base: valid iff (uint)(kbs+bq+r)<=511

    // ---- precomputed staging offsets (lane-invariant across tiles) ----
    // K slot s=tid(+256): row=s>>4, chunk-slot holds global chunk (s&15)^(row&7)
    const uint okg0 = ((uint)(tid >> 4)) * 128 + (uint)(((tid & 15) ^ ((tid >> 4) & 7)) << 3);
    // V slot s=tid(+256): row=s>>2, chunk-slot holds global chunk (s&3)^((row>>1)&3)
    const uint ovg0 = ((uint)(tid >> 2)) * T_SEQ + (uint)(((tid & 3) ^ ((tid >> 3) & 3)) << 3);
    char* const ldsK0 = (char*)&Kls[0][0] + tid * 16;
    char* const ldsK1 = (char*)&Kls[1][0] + tid * 16;
    char* const ldsV0 = (char*)&Vls[0][0] + tid * 16;
    char* const ldsV1 = (char*)&Vls[1][0] + tid * 16;

    // ---- precomputed K/V LDS read bases ----
    // K addr(kc,half) = base + [(kc*64+g*16) ^ ((lq&7)<<4)] + half*4096
    //                 = (base + blo + e6sel(kc)) + (kc>>1)*128 + half*4096
    const uint e6  = (lane & 4) << 4;                 // (lq&4)<<4: 0 or 64
    const uint blo = (uint)((g * 16) ^ ((lq & 3) << 4));
    const char* kbA_e = (const char*)&Kls[0][0] + lq * 256 + blo + e6;
    const char* kbA_o = (const char*)&Kls[0][0] + lq * 256 + blo + (64 - e6);
    const char* kbB_e = (const char*)&Kls[1][0] + lq * 256 + blo + e6;
    const char* kbB_o = (const char*)&Kls[1][0] + lq * 256 + blo + (64 - e6);
    const uint vswz = (uint)((g ^ ((lq >> 1) & 3)) << 4);
    const char* vbA = (const char*)&Vls[0][0] + lq * 64 + vswz;
    const char* vbB = (const char*)&Vls[1][0] + lq * 64 + vswz;

    ushort* const pw0 = &Plds[wv][lq][4 * g];
    ushort* const pw1 = pw0 + 16;
    const ushort* const prd = &Plds[wv][lq][8 * g];

    auto stage = [&](char* lk, char* lv, int kbs_) {
        const bf16_t* kt_ = kb_ + (size_t)kbs_ * 128;   // uniform (SGPR)
        const bf16_t* vt_ = vb_ + kbs_;
        gld16(kt_ + okg0,          lk);
        gld16(kt_ + 2048 + okg0,   lk + 4096);
        gld16(vt_ + ovg0,          lv);
        gld16(vt_ + 524288 + ovg0, lv + 4096);          // +64 rows * 8192
    };

    auto compute = [&](const char* kbe, const char* kbo, const char* vbp, int kbs_) {
        if (kbs_ + 31 < wlow || kbs_ > q0w + 15) return;   // wave-uniform

        f32x4 s0 = {0.f, 0.f, 0.f, 0.f}, s1 = {0.f, 0.f, 0.f, 0.f};
        __builtin_amdgcn_s_setprio(1);
#pragma unroll
        for (int kc = 0; kc < 4; ++kc) {
            const char* pa = (kc & 1) ? kbo : kbe;
            const int  off = (kc >> 1) * 128;
            bf16x8 k0 = *(const bf16x8*)(pa + off);
            bf16x8 k1 = *(const bf16x8*)(pa + off + 4096);
            s0 = __builtin_amdgcn_mfma_f32_16x16x32_bf16(k0, qf[kc], s0, 0, 0, 0);
            s1 = __builtin_amdgcn_mfma_f32_16x16x32_bf16(k1, qf[kc], s1, 0, 0, 0);
        }
        __builtin_amdgcn_s_setprio(0);

        float sv[8];
        const bool interior = (kbs_ >= q0w - 496) && (kbs_ + 31 <= q0w);
        if (interior) {
#pragma unroll
            for (int r = 0; r < 4; ++r) { sv[r] = s0[r]; sv[4 + r] = s1[r]; }
        } else {
            const int b0 = kbs_ + bq;
#pragma unroll
            for (int r = 0; r < 4; ++r) {
                sv[r]     = ((uint)(b0 + r)      <= 511u) ? s0[r] : -1e30f;
                sv[4 + r] = ((uint)(b0 + 16 + r) <= 511u) ? s1[r] : -1e30f;
            }
        }

        float tm = sv[0];
#pragma unroll
        for (int i = 1; i < 8; ++i) tm = fmaxf(tm, sv[i]);
        tm = fmaxf(tm, __shfl_xor(tm, 16));
        tm = fmaxf(tm, __shfl_xor(tm, 32));
        const float tms = tm * SCL2E;

        if (!__all(tms <= mrun + 11.54f)) {   // defer-max (8 nats = 11.54 bits)
            float mnew  = fmaxf(mrun, tms);
            float alpha = __builtin_amdgcn_exp2f(mrun - mnew);
            lsum *= alpha;
#pragma unroll
            for (int i = 0; i < 8; ++i) acc[i] *= alpha;
            mrun = mnew;
        }

        float p[8];
        float ps = 0.f;
#pragma unroll
        for (int i = 0; i < 8; ++i) {
            p[i] = __builtin_amdgcn_exp2f(fmaf(sv[i], SCL2E, -mrun));
            ps += p[i];
        }
        ps += __shfl_xor(ps, 16);
        ps += __shfl_xor(ps, 32);
        lsum += ps;

        U4 w0, w1;
        w0.b[0] = (bf16_t)p[0]; w0.b[1] = (bf16_t)p[1]; w0.b[2] = (bf16_t)p[2]; w0.b[3] = (bf16_t)p[3];
        w1.b[0] = (bf16_t)p[4]; w1.b[1] = (bf16_t)p[5]; w1.b[2] = (bf16_t)p[6]; w1.b[3] = (bf16_t)p[7];
        *(uint2*)(void*)pw0 = w0.u;
        *(uint2*)(void*)pw1 = w1.u;
        asm volatile("s_waitcnt lgkmcnt(0)" ::: "memory");
        bf16x8 pb = *(const bf16x8*)(const void*)prd;

        __builtin_amdgcn_s_setprio(1);
#pragma unroll
        for (int dt = 0; dt < 8; ++dt) {
            bf16x8 vf = *(const bf16x8*)(vbp + dt * 1024);
            acc[dt] = __builtin_amdgcn_mfma_f32_16x16x32_bf16(vf, pb, acc[dt], 0, 0, 0);
        }
        __builtin_amdgcn_s_setprio(0);
    };

    // ---- 2-phase (A/B buffer) pipelined loop, block-uniform control ----
    stage(ldsK0, ldsV0, ktb0 << 5);
    __syncthreads();

    int kt = ktb0;
    while (kt + 1 <= ktb1) {
        stage(ldsK1, ldsV1, (kt + 1) << 5);
        compute(kbA_e, kbA_o, vbA, kt << 5);
        __syncthreads();
        if (kt + 2 <= ktb1) stage(ldsK0, ldsV0, (kt + 2) << 5);
        compute(kbB_e, kbB_o, vbB, (kt + 1) << 5);
        __syncthreads();
        kt += 2;
    }
    if (kt <= ktb1) compute(kbA_e, kbA_o, vbA, kt << 5);

    // ---- epilogue ----
    float inv = 1.0f / lsum;
#pragma unroll
    for (int dt = 0; dt < 8; ++dt) {
        float4 o;
        o.x = acc[dt][0] * inv; o.y = acc[dt][1] * inv;
        o.z = acc[dt][2] * inv; o.w = acc[dt][3] * inv;
        *(float4*)(out + (size_t)qa * 2048 + h * 128 + dt * 16 + 4 * g) = o;
    }
    if (lane < 16) {
        out[(size_t)T_SEQ * 2048 + (size_t)h * T_SEQ + qa] =
            LN2 * (mrun + log2f(lsum));
    }
}

extern "C" void kernel_launch(void* const* d_in, const int* in_sizes, int n_in,
                              void* d_out, int out_size, void* d_ws, size_t ws_size,
                              hipStream_t stream) {
    const float* q = (const float*)d_in[0];
    const float* k = (const float*)d_in[1];
    const float* v = (const float*)d_in[2];
    float* out = (float*)d_out;

    bf16_t* Kb = (bf16_t*)d_ws;
    bf16_t* Vt = Kb + (size_t)HK_KV * T_SEQ * D_HD;

    prep_kv<<<4096 + HK_KV * (T_SEQ / 64) * (D_HD / 64), 256, 0, stream>>>(k, v, Kb, Vt);
    attn_main<<<(T_SEQ / 64) * H_Q, 256, 0, stream>>>(q, Kb, Vt, out);
}